// Round 1
// baseline (227.497 us; speedup 1.0000x reference)
//
#include <hip/hip_runtime.h>
#include <stdint.h>

#define DEV static __device__ __forceinline__

typedef __attribute__((ext_vector_type(4))) float f32x4;
typedef __attribute__((ext_vector_type(8))) short bf16x8;               // 8 bf16 in 4 VGPR (guide §3)
typedef bf16x8 __attribute__((may_alias)) bf16x8_a;
typedef __attribute__((ext_vector_type(2))) unsigned int u32x2;
typedef u32x2 __attribute__((may_alias)) u32x2_a;

DEV unsigned short f2bf(float f) {
  union { float f; unsigned int u; } v; v.f = f;
  return (unsigned short)((v.u + 0x7FFFu + ((v.u >> 16) & 1u)) >> 16);  // RNE
}

DEV void gload_lds16(const void* g, void* l) {
  __builtin_amdgcn_global_load_lds(
      (const __attribute__((address_space(1))) unsigned int*)g,
      (__attribute__((address_space(3))) unsigned int*)l, 16, 0, 0);
}

// ---------------- prep kernels ----------------
__global__ void cast_bf16_k(const float4* __restrict__ in, ushort4* __restrict__ out, int n4) {
  int i = blockIdx.x * 256 + threadIdx.x;
  if (i >= n4) return;
  float4 f = in[i];
  ushort4 o; o.x = f2bf(f.x); o.y = f2bf(f.y); o.z = f2bf(f.z); o.w = f2bf(f.w);
  out[i] = o;
}

// in: fp32 [R][C]  ->  out: bf16 [C][R]
__global__ __launch_bounds__(256) void transpose_bf16_k(const float* __restrict__ in,
                                                        unsigned short* __restrict__ out,
                                                        int R, int C) {
  __shared__ float tile[32][33];
  const int t = threadIdx.x;
  const int r = t >> 3, c4 = (t & 7) << 2;
  const int tr = blockIdx.y << 5, tc = blockIdx.x << 5;
  const float4 v = *(const float4*)(in + (size_t)(tr + r) * C + tc + c4);
  tile[r][c4] = v.x; tile[r][c4 + 1] = v.y; tile[r][c4 + 2] = v.z; tile[r][c4 + 3] = v.w;
  __syncthreads();
  ushort4 o;
  o.x = f2bf(tile[c4][r]); o.y = f2bf(tile[c4 + 1][r]);
  o.z = f2bf(tile[c4 + 2][r]); o.w = f2bf(tile[c4 + 3][r]);
  *(ushort4*)(out + (size_t)(tc + r) * R + tr + c4) = o;
}

// ---------------- GEMM: C[M,N] = A[M,K] * BT[N,K]^T, bf16 in, fp32 acc ----------------
// EPI==0: fp32 C + bias.  EPI==1: scatter to q (x0.125) / k [B,H,S,64] and vT [B,H,64,S], bf16.
template <int EPI>
__global__ __launch_bounds__(256) void gemm_bt(const unsigned short* __restrict__ A,
                                               const unsigned short* __restrict__ BT,
                                               const float* __restrict__ bias,
                                               float* __restrict__ Cout,
                                               unsigned short* __restrict__ q_buf,
                                               unsigned short* __restrict__ k_buf,
                                               unsigned short* __restrict__ vT_buf,
                                               int M, int N, int K) {
  __shared__ unsigned short As[128 * 64];
  __shared__ unsigned short Bs[128 * 64];
  const int t = threadIdx.x, w = t >> 6, l = t & 63;
  const int wm = w >> 1, wn = w & 1;
  const int lg = l >> 4, ln = l & 15;
  const int m0 = blockIdx.y * 128, n0 = blockIdx.x * 128;
  const int rr = w * 32 + (l >> 3);   // +j*8 ; LDS dest = uniform base + 16*lane (gload_lds rule)
  const int cc = (l & 7) * 8;

  f32x4 acc[4][4] = {};

  for (int k0 = 0; k0 < K; k0 += 64) {
#pragma unroll
    for (int j = 0; j < 4; ++j) {
      gload_lds16(A + (size_t)(m0 + rr + j * 8) * K + k0 + cc, &As[(rr + j * 8) * 64 + cc]);
      gload_lds16(BT + (size_t)(n0 + rr + j * 8) * K + k0 + cc, &Bs[(rr + j * 8) * 64 + cc]);
    }
    __syncthreads();   // drains vmcnt before barrier (compiler-emitted)
#pragma unroll
    for (int kk = 0; kk < 2; ++kk) {
      bf16x8 af[4], bfr[4];
#pragma unroll
      for (int mi = 0; mi < 4; ++mi)
        af[mi] = *(const bf16x8_a*)&As[(wm * 64 + mi * 16 + ln) * 64 + kk * 32 + lg * 8];
#pragma unroll
      for (int ni = 0; ni < 4; ++ni)
        bfr[ni] = *(const bf16x8_a*)&Bs[(wn * 64 + ni * 16 + ln) * 64 + kk * 32 + lg * 8];
#pragma unroll
      for (int mi = 0; mi < 4; ++mi)
#pragma unroll
        for (int ni = 0; ni < 4; ++ni)
          acc[mi][ni] = __builtin_amdgcn_mfma_f32_16x16x32_bf16(af[mi], bfr[ni], acc[mi][ni], 0, 0, 0);
    }
    __syncthreads();
  }

  // epilogue: C/D layout col = lane&15, row = (lane>>4)*4 + reg  (m89-verified)
#pragma unroll
  for (int ni = 0; ni < 4; ++ni) {
    const int c = n0 + wn * 64 + ni * 16 + ln;
    const float bv = bias[c];
    if (EPI == 1) {
      const int which = c >> 10;          // 0:q 1:k 2:v   (wave-uniform: 64-aligned col blocks)
      const int h = (c >> 6) & 15;
      const int d = c & 63;
#pragma unroll
      for (int mi = 0; mi < 4; ++mi) {
        const int mrow = m0 + wm * 64 + mi * 16 + lg * 4;
        const int b = mrow >> 11, s = mrow & 2047;
        const size_t bh = (size_t)(b * 16 + h);
        f32x4 v = acc[mi][ni];
        if (which == 0) {
          unsigned short* dst = q_buf + (bh * 2048 + s) * 64 + d;
#pragma unroll
          for (int r = 0; r < 4; ++r) dst[(size_t)r * 64] = f2bf((v[r] + bv) * 0.125f); // hd^-0.5 folded (exact pow2)
        } else if (which == 1) {
          unsigned short* dst = k_buf + (bh * 2048 + s) * 64 + d;
#pragma unroll
          for (int r = 0; r < 4; ++r) dst[(size_t)r * 64] = f2bf(v[r] + bv);
        } else {
          unsigned short* dst = vT_buf + (bh * 64 + d) * 2048 + s;   // 4 consecutive s -> 8B store
          ushort4 o4;
          o4.x = f2bf(v[0] + bv); o4.y = f2bf(v[1] + bv); o4.z = f2bf(v[2] + bv); o4.w = f2bf(v[3] + bv);
          *(ushort4*)dst = o4;
        }
      }
    } else {
#pragma unroll
      for (int mi = 0; mi < 4; ++mi) {
        const int mrow = m0 + wm * 64 + mi * 16 + lg * 4;
        f32x4 v = acc[mi][ni];
#pragma unroll
        for (int r = 0; r < 4; ++r) Cout[(size_t)(mrow + r) * N + c] = v[r] + bv;
      }
    }
  }
}

// ---------------- flash attention ----------------
// grid 512: block = (bh, q-tile of 128). 4 waves x 32 q-rows. KV tile = 64.
// Swapped QK^T: sa = mfma(K,Q) -> D[m=kj][n=qi]; softmax reduce = in-reg + shfl_xor(16,32).
// P roundtrips a per-wave LDS buffer (no barriers needed). V read from vT (contiguous kj).
__global__ __launch_bounds__(256) void attn_k(const unsigned short* __restrict__ Qb,
                                              const unsigned short* __restrict__ Kb,
                                              const unsigned short* __restrict__ Vt,
                                              unsigned short* __restrict__ AO) {
  __shared__ unsigned short P_lds[4][32][72];   // stride 144B: 16B-aligned b128, low conflict
  const int t = threadIdx.x, w = t >> 6, l = t & 63;
  const int lg = l >> 4, ln = l & 15;
  const int bh = blockIdx.x >> 4;
  const int qt = blockIdx.x & 15;
  const int b = bh >> 4, h = bh & 15;
  const unsigned short* Q = Qb + (size_t)bh * 2048 * 64;
  const unsigned short* K = Kb + (size_t)bh * 2048 * 64;
  const unsigned short* V = Vt + (size_t)bh * 64 * 2048;
  const int qbase = qt * 128 + w * 32;

  bf16x8 qf[2][2];
#pragma unroll
  for (int nj = 0; nj < 2; ++nj)
#pragma unroll
    for (int kd = 0; kd < 2; ++kd)
      qf[nj][kd] = *(const bf16x8_a*)(Q + (size_t)(qbase + nj * 16 + ln) * 64 + kd * 32 + lg * 8);

  f32x4 o[2][4] = {};
  float m0r = -1e30f, m1r = -1e30f, l0r = 0.f, l1r = 0.f;

  for (int tk = 0; tk < 32; ++tk) {
    const int k0 = tk * 64;
    bf16x8 kf[4][2];
#pragma unroll
    for (int mk = 0; mk < 4; ++mk)
#pragma unroll
      for (int kd = 0; kd < 2; ++kd)
        kf[mk][kd] = *(const bf16x8_a*)(K + (size_t)(k0 + mk * 16 + ln) * 64 + kd * 32 + lg * 8);

    f32x4 sa[4][2] = {};
#pragma unroll
    for (int mk = 0; mk < 4; ++mk)
#pragma unroll
      for (int nj = 0; nj < 2; ++nj)
#pragma unroll
        for (int kd = 0; kd < 2; ++kd)
          sa[mk][nj] = __builtin_amdgcn_mfma_f32_16x16x32_bf16(kf[mk][kd], qf[nj][kd], sa[mk][nj], 0, 0, 0);

    // row max (rows = qi = ln, per nj): 16 in-register + 2 shuffles
    float t0 = -1e30f, t1 = -1e30f;
#pragma unroll
    for (int mk = 0; mk < 4; ++mk)
#pragma unroll
      for (int r = 0; r < 4; ++r) {
        t0 = fmaxf(t0, sa[mk][0][r]);
        t1 = fmaxf(t1, sa[mk][1][r]);
      }
    t0 = fmaxf(t0, __shfl_xor(t0, 16)); t0 = fmaxf(t0, __shfl_xor(t0, 32));
    t1 = fmaxf(t1, __shfl_xor(t1, 16)); t1 = fmaxf(t1, __shfl_xor(t1, 32));
    const float mn0 = fmaxf(m0r, t0), mn1 = fmaxf(m1r, t1);
    const float a0 = __expf(m0r - mn0), a1 = __expf(m1r - mn1);
    m0r = mn0; m1r = mn1;

    float rs0 = 0.f, rs1 = 0.f;
#pragma unroll
    for (int mk = 0; mk < 4; ++mk)
#pragma unroll
      for (int nj = 0; nj < 2; ++nj) {
        const float mn = nj ? mn1 : mn0;
        const float p0 = __expf(sa[mk][nj][0] - mn);
        const float p1 = __expf(sa[mk][nj][1] - mn);
        const float p2 = __expf(sa[mk][nj][2] - mn);
        const float p3 = __expf(sa[mk][nj][3] - mn);
        if (nj) rs1 += (p0 + p1) + (p2 + p3); else rs0 += (p0 + p1) + (p2 + p3);
        u32x2 pk;
        pk.x = (unsigned)f2bf(p0) | ((unsigned)f2bf(p1) << 16);
        pk.y = (unsigned)f2bf(p2) | ((unsigned)f2bf(p3) << 16);
        *(u32x2_a*)&P_lds[w][nj * 16 + ln][mk * 16 + lg * 4] = pk;   // P[qi][kj]
      }
    rs0 += __shfl_xor(rs0, 16); rs0 += __shfl_xor(rs0, 32);
    rs1 += __shfl_xor(rs1, 16); rs1 += __shfl_xor(rs1, 32);
    l0r = l0r * a0 + rs0;
    l1r = l1r * a1 + rs1;

    // rescale O (row layout qi = lg*4+r [+16*mi]) by alpha broadcast from col layout
#pragma unroll
    for (int r = 0; r < 4; ++r) {
      const int src = lg * 4 + r;
      const float x0 = __shfl(a0, src);
      const float x1 = __shfl(a1, src);
#pragma unroll
      for (int nd = 0; nd < 4; ++nd) { o[0][nd][r] *= x0; o[1][nd][r] *= x1; }
    }

    // PV: A = P from LDS (contiguous kj), B = V from vT (contiguous kj)
    bf16x8 pf0[2], pf1[2];
#pragma unroll
    for (int ks = 0; ks < 2; ++ks) {
      pf0[ks] = *(const bf16x8_a*)&P_lds[w][ln][ks * 32 + lg * 8];
      pf1[ks] = *(const bf16x8_a*)&P_lds[w][16 + ln][ks * 32 + lg * 8];
    }
#pragma unroll
    for (int ks = 0; ks < 2; ++ks)
#pragma unroll
      for (int nd = 0; nd < 4; ++nd) {
        const bf16x8 vf = *(const bf16x8_a*)(V + (size_t)(nd * 16 + ln) * 2048 + k0 + ks * 32 + lg * 8);
        o[0][nd] = __builtin_amdgcn_mfma_f32_16x16x32_bf16(pf0[ks], vf, o[0][nd], 0, 0, 0);
        o[1][nd] = __builtin_amdgcn_mfma_f32_16x16x32_bf16(pf1[ks], vf, o[1][nd], 0, 0, 0);
      }
  }

  const float i0v = 1.0f / l0r, i1v = 1.0f / l1r;
  float i0[4], i1[4];
#pragma unroll
  for (int r = 0; r < 4; ++r) {
    const int src = lg * 4 + r;
    i0[r] = __shfl(i0v, src);
    i1[r] = __shfl(i1v, src);
  }
#pragma unroll
  for (int mi = 0; mi < 2; ++mi)
#pragma unroll
    for (int nd = 0; nd < 4; ++nd)
#pragma unroll
      for (int r = 0; r < 4; ++r) {
        const float iv = mi ? i1[r] : i0[r];
        const size_t row = (size_t)b * 2048 + qbase + mi * 16 + lg * 4 + r;
        AO[row * 1024 + h * 64 + nd * 16 + ln] = f2bf(o[mi][nd][r] * iv);
      }
}

// ---------------- launcher ----------------
extern "C" void kernel_launch(void* const* d_in, const int* in_sizes, int n_in,
                              void* d_out, int out_size, void* d_ws, size_t ws_size,
                              hipStream_t stream) {
  const float* query = (const float*)d_in[0];
  // d_in[1]=key, d_in[2]=value: unused (reference derives q,k,v from query)
  const float* W_qkv = (const float*)d_in[3];
  const float* b_qkv = (const float*)d_in[4];
  const float* W_out = (const float*)d_in[5];
  const float* b_out = (const float*)d_in[6];
  float* out = (float*)d_out;
  char* ws = (char*)d_ws;

  // ws layout (41.9 MB): [Xb/AO 8MB][WqkvT 6MB][WoutT 2MB][qb 8MB][kb 8MB][vT 8MB]
  unsigned short* Xb    = (unsigned short*)(ws);
  unsigned short* WqkvT = (unsigned short*)(ws + 8388608);
  unsigned short* WoutT = (unsigned short*)(ws + 14680064);
  unsigned short* qb    = (unsigned short*)(ws + 16777216);
  unsigned short* kb    = (unsigned short*)(ws + 25165824);
  unsigned short* vT    = (unsigned short*)(ws + 33554432);
  unsigned short* AO    = Xb;  // Xb dead after gemm1; reuse for attention output

  cast_bf16_k<<<4096, 256, 0, stream>>>((const float4*)query, (ushort4*)Xb, 1048576);
  transpose_bf16_k<<<dim3(96, 32), 256, 0, stream>>>(W_qkv, WqkvT, 1024, 3072);
  transpose_bf16_k<<<dim3(32, 32), 256, 0, stream>>>(W_out, WoutT, 1024, 1024);
  gemm_bt<1><<<dim3(24, 32), 256, 0, stream>>>(Xb, WqkvT, b_qkv, nullptr, qb, kb, vT, 4096, 3072, 1024);
  attn_k<<<512, 256, 0, stream>>>(qb, kb, vT, AO);
  gemm_bt<0><<<dim3(8, 32), 256, 0, stream>>>(AO, WoutT, b_out, out, nullptr, nullptr, nullptr, 4096, 1024, 1024);
}